// Round 6
// baseline (85.911 us; speedup 1.0000x reference)
//
#include <hip/hip_runtime.h>

// JPEG-compression-as-augmentation, collapsed to luma-only per-channel codec.
// Chroma planes of a gray (v,v,v) image are exactly 128 and the chroma codec
// is an exact fixed point, so only the Y path survives. Per (B,C) channel:
//   min/max normalize -> *255 -> edge-pad 14x14 -> 16x16 -> 4 blocks of 8x8
//   R = C^T * diffround( C*(X-128)*C^T / (Y_T*f) ) * (Y_T*f) * C + 128
//   out = clip(R,0,255)/255 * rng + min        (f = 0.02 at quality 99)
//
// Round-10: CUT DS-PIPE OPS ~2x. Theory from rounds 5-9: LDS-transpose and
// register-shuffle dataflows both land ~20-25us because __shfl_xor IS a
// DS-pipe op (ds_swizzle) — both structures issue ~66-80 DS wave-ops/chunk
// and the DS pipe (~5cyc/op x 32 waves/CU) is the binding resource; VALU
// (~7us) hides under it. Changes:
//  * IDCT re-association kills one transpose: Z = C^T*Qs computed DIRECTLY
//    from column-held Qs (z_r = COLDOT(r,g), no data movement), then ONE
//    transpose, then R-row = Z*C. 2 transposes/chunk instead of 3. (Sum
//    order differs by ulps on post-quant LINEAR math only — no rint
//    downstream; threshold 0.108 vs 0.0156 current.)
//  * DPP instead of DS for xor1/xor2/xor8 cross-lane moves: quad_perm
//    0xB1/0x4E and row_ror:8 are VALU-pipe ops, zero DS traffic. Only
//    xor4/xor16 remain DS. DS ops/chunk: ~66 -> ~31.
//  * final scatter is now ROW-held (lane owns padded row prb+i, 8 cols).
// Attribution history kept:
//  * round-8: scratch was SROA failure on float[8] locals, NOT allocator
//    pressure (lb change left VGPR=32, WRITE=146MB). Round-9 named scalars
//    fixed it (kernel 80us -> <44us).
//  * round-7: "#pragma unroll 1" chunk loop => WRONG RESULTS. Loop stays
//    FULLY UNROLLED.
// Retained: 2-deep pipeline (both chunks' global_load_lds issued before ONE
// vmcnt(0)), LDS = raw double buffer (12.5KB) with output plane reusing the
// dead raw region, no s_barrier anywhere, transposed prescaled quant table,
// EXACT fp32 quant divide (round-boundary sensitive — do not trade ulps),
// float4 global I/O, lb(256,4).

namespace {

constexpr int CH_PER_WG = 8;       // 4 waves * 2 channels
constexpr int HW        = 196;     // 14*14
constexpr int CPW       = 2 * HW;  // floats per wave per chunk (2 channels)
constexpr int CHUNK_F   = CH_PER_WG * HW;  // 1568 floats per chunk per block

// Orthonormal 8-point DCT-II matrix: CM[u][x] = 0.5*alpha_u*cos((2x+1)u*pi/16).
// Only ever indexed with compile-time literals -> folds to inline constants.
constexpr float CM[8][8] = {
  { 0.35355339059327376f,  0.35355339059327376f,  0.35355339059327376f,  0.35355339059327376f,
    0.35355339059327376f,  0.35355339059327376f,  0.35355339059327376f,  0.35355339059327376f},
  { 0.49039264020161522f,  0.41573480615127262f,  0.27778511650980114f,  0.09754516100806417f,
   -0.09754516100806417f, -0.27778511650980114f, -0.41573480615127262f, -0.49039264020161522f},
  { 0.46193976625564337f,  0.19134171618254492f, -0.19134171618254492f, -0.46193976625564337f,
   -0.46193976625564337f, -0.19134171618254492f,  0.19134171618254492f,  0.46193976625564337f},
  { 0.41573480615127262f, -0.09754516100806417f, -0.49039264020161522f, -0.27778511650980114f,
    0.27778511650980114f,  0.49039264020161522f,  0.09754516100806417f, -0.41573480615127262f},
  { 0.35355339059327376f, -0.35355339059327376f, -0.35355339059327376f,  0.35355339059327376f,
    0.35355339059327376f, -0.35355339059327376f, -0.35355339059327376f,  0.35355339059327376f},
  { 0.27778511650980114f, -0.49039264020161522f,  0.09754516100806417f,  0.41573480615127262f,
   -0.41573480615127262f, -0.09754516100806417f,  0.49039264020161522f, -0.27778511650980114f},
  { 0.19134171618254492f, -0.46193976625564337f,  0.46193976625564337f, -0.19134171618254492f,
   -0.19134171618254492f,  0.46193976625564337f, -0.46193976625564337f,  0.19134171618254492f},
  { 0.09754516100806417f, -0.27778511650980114f,  0.41573480615127262f, -0.49039264020161522f,
    0.49039264020161522f, -0.41573480615127262f,  0.27778511650980114f, -0.09754516100806417f},
};

} // namespace

// Transposed, pre-scaled luma quant table: QVT[i][k] = Y_T[k][i] * 0.02f.
// int*0.02f is constant-folded in IEEE fp32 RN -> bit-identical to the
// runtime v_mul of earlier rounds. Row i is 16B-aligned: one lane reads its
// whole column as two float4 while the staging DMA is in flight.
#define SF 0.02f
__device__ __align__(16) const float QVT[8][8] = {
  {16*SF, 12*SF, 14*SF, 14*SF, 18*SF,  24*SF,  49*SF,  72*SF},
  {11*SF, 12*SF, 13*SF, 17*SF, 22*SF,  35*SF,  64*SF,  92*SF},
  {10*SF, 14*SF, 16*SF, 22*SF, 37*SF,  55*SF,  78*SF,  95*SF},
  {16*SF, 19*SF, 24*SF, 29*SF, 56*SF,  64*SF,  87*SF,  98*SF},
  {24*SF, 26*SF, 40*SF, 51*SF, 68*SF,  81*SF, 103*SF, 112*SF},
  {40*SF, 58*SF, 57*SF, 87*SF, 109*SF, 104*SF, 121*SF, 100*SF},
  {51*SF, 60*SF, 69*SF, 80*SF, 103*SF, 113*SF, 120*SF, 103*SF},
  {61*SF, 55*SF, 56*SF, 62*SF, 77*SF,  92*SF, 101*SF,  99*SF},
};
#undef SF

// Intra-wave fences. All producers and consumers of any LDS/VMEM data are in
// the same wave, so no s_barrier exists anywhere in the kernel.
#define WAVE_LDS_SYNC() asm volatile("s_waitcnt lgkmcnt(0)" ::: "memory")
#define WAVE_VM_SYNC()  asm volatile("s_waitcnt vmcnt(0)" ::: "memory")

typedef __attribute__((address_space(1))) const void gvoid_t;
typedef __attribute__((address_space(3))) void       lvoid_t;

// Dot products as explicit fmaf chains, SAME nesting order as the original
// "s=0; for j: s=fmaf(x[j],C,s)" loop -> bit-identical results.
// ROWDOT: sum_j x_j * CM[K][j]   COLDOT: sum_j x_j * CM[j][K]
#define ROWDOT(K, x0,x1,x2,x3,x4,x5,x6,x7) \
  fmaf(x7, CM[K][7], fmaf(x6, CM[K][6], fmaf(x5, CM[K][5], fmaf(x4, CM[K][4], \
  fmaf(x3, CM[K][3], fmaf(x2, CM[K][2], fmaf(x1, CM[K][1], fmaf(x0, CM[K][0], 0.0f))))))))
#define COLDOT(K, x0,x1,x2,x3,x4,x5,x6,x7) \
  fmaf(x7, CM[7][K], fmaf(x6, CM[6][K], fmaf(x5, CM[5][K], fmaf(x4, CM[4][K], \
  fmaf(x3, CM[3][K], fmaf(x2, CM[2][K], fmaf(x1, CM[1][K], fmaf(x0, CM[0][K], 0.0f))))))))

// Cross-lane xor moves on the VALU pipe via DPP (zero DS traffic).
// quad_perm {1,0,3,2}=0xB1 -> lane^1; {2,3,0,1}=0x4E -> lane^2;
// row_ror:8 = 0x128 -> lane^8 within each 16-lane row.
template<int CTRL>
__device__ __forceinline__ float fdpp(float v) {
  return __builtin_bit_cast(float,
      __builtin_amdgcn_mov_dpp(__builtin_bit_cast(int, v), CTRL, 0xF, 0xF, true));
}

// One butterfly step of the exact 8x8 lane-group transpose, on NAMED
// scalars (pure selects + a cross-lane move, no memory). up lane
// ((i&d)==0) exchanges its B with the partner's A. Bit-identical.
// XSTD: partner via DPP (VALU pipe).  XSTS: partner via shfl (DS pipe).
#define XSTD(CTRL, A, B) { float snd_ = upd_ ? (B) : (A); \
                           float got_ = fdpp<(CTRL)>(snd_); \
                           (A) = upd_ ? (A) : got_; \
                           (B) = upd_ ? got_ : (B); }
#define XSTS(D, A, B) { float snd_ = upd_ ? (B) : (A); \
                        float got_ = __shfl_xor(snd_, (D), 64); \
                        (A) = upd_ ? (A) : got_; \
                        (B) = upd_ ? got_ : (B); }

// Full transpose: element (reg r, lane l) -> (reg l, lane r) within each
// 8-lane group. Stages d=1 (DPP quad_perm), d=2 (DPP quad_perm), d=4 (DS).
#define XPOSE8(x0,x1,x2,x3,x4,x5,x6,x7, LANE) { \
  { const bool upd_ = ((LANE) & 1) == 0; \
    XSTD(0xB1, x0, x1) XSTD(0xB1, x2, x3) XSTD(0xB1, x4, x5) XSTD(0xB1, x6, x7) } \
  { const bool upd_ = ((LANE) & 2) == 0; \
    XSTD(0x4E, x0, x2) XSTD(0x4E, x1, x3) XSTD(0x4E, x4, x6) XSTD(0x4E, x5, x7) } \
  { const bool upd_ = ((LANE) & 4) == 0; \
    XSTS(4, x0, x4) XSTS(4, x1, x5) XSTS(4, x2, x6) XSTS(4, x3, x7) } }

__global__ __launch_bounds__(256, 4)
void jpeg_codec_kernel(const float* __restrict__ x, float* __restrict__ out) {
  // Double-buffered raw staging; the output plane reuses the current chunk's
  // buffer (raw is dead after pass 1). 12544 B/block.
  __shared__ __align__(16) float s_raw[2][4 * CPW];

  const int tid = threadIdx.x;
  const int w   = tid >> 6;       // wave 0..3
  const int wl  = tid & 63;       // lane in wave
  const int chl = (tid >> 5) & 1; // channel-in-wave 0/1
  const int l   = tid & 31;       // lane-in-channel
  const int b   = l >> 3;         // block 0..3
  const int i   = l & 7;          // row/col 0..7

  const long long c0 = 2LL * blockIdx.x;  // first of this block's two chunks

  // ---- 1. issue BOTH chunks' staging DMA back-to-back ----
  // global_load_lds writes lane j's 16B to (uniform lds base) + j*16 — the
  // contiguous layout we want. 2 vmem ops per chunk per wave.
  #pragma unroll
  for (int p = 0; p < 2; ++p) {
    const float4* x4 = (const float4*)x + (c0 + p) * (CHUNK_F / 4) + w * (CPW / 4);
    float* raw = &s_raw[p][w * CPW];
    __builtin_amdgcn_global_load_lds((gvoid_t*)(x4 + wl), (lvoid_t*)raw, 16, 0, 0);
    if (wl < CPW / 4 - 64)  // lanes 0..33 stage f4 64..97
      __builtin_amdgcn_global_load_lds((gvoid_t*)(x4 + 64 + wl),
                                       (lvoid_t*)(raw + 256), 16, 0, 0);
  }

  // per-lane quant column as NAMED scalars, loaded while DMAs are in flight
  float qv0, qv1, qv2, qv3, qv4, qv5, qv6, qv7;
  {
    const float4* qt = (const float4*)QVT[i];
    float4 qa = qt[0], qb = qt[1];
    qv0 = qa.x; qv1 = qa.y; qv2 = qa.z; qv3 = qa.w;
    qv4 = qb.x; qv5 = qb.y; qv6 = qb.z; qv7 = qb.w;
  }

  // Single cold stall per block: both chunks were issued together and arrive
  // back-to-back, so draining to 0 costs barely more than waiting chunk 0.
  WAVE_VM_SYNC();

  #pragma unroll
  for (int p = 0; p < 2; ++p) {
    float* rawp = &s_raw[p][w * CPW];
    const float* raw_ch = rawp + chl * HW;  // this lane's channel raw

    // ---- 2. per-channel min/max: float4 reads + mixed DPP/DS butterfly ----
    // fminf/fmaxf are exact, commutative, associative -> stage order is free.
    float mn, inv, scale;        // uniform within the 32-lane channel group
    {
      float vmin = 1e30f, vmax = -1e30f;
      const float4* c4 = (const float4*)raw_ch;     // offsets %16 == 0
      {
        float4 v = c4[l];                           // f4 0..31
        vmin = fminf(fminf(vmin, v.x), fminf(v.y, fminf(v.z, v.w)));
        vmax = fmaxf(fmaxf(vmax, v.x), fmaxf(v.y, fmaxf(v.z, v.w)));
      }
      if (l < 17) {                                 // f4 32..48
        float4 v = c4[l + 32];
        vmin = fminf(fminf(vmin, v.x), fminf(v.y, fminf(v.z, v.w)));
        vmax = fmaxf(fmaxf(vmax, v.x), fmaxf(v.y, fmaxf(v.z, v.w)));
      }
      vmin = fminf(vmin, __shfl_xor(vmin, 16, 64)); // xor16 crosses DPP rows: DS
      vmax = fmaxf(vmax, __shfl_xor(vmax, 16, 64));
      vmin = fminf(vmin, fdpp<0x128>(vmin));        // xor8 = row_ror:8 (VALU)
      vmax = fmaxf(vmax, fdpp<0x128>(vmax));
      vmin = fminf(vmin, __shfl_xor(vmin, 4, 64));  // xor4: DS
      vmax = fmaxf(vmax, __shfl_xor(vmax, 4, 64));
      vmin = fminf(vmin, fdpp<0x4E>(vmin));         // xor2 quad_perm (VALU)
      vmax = fmaxf(vmax, fdpp<0x4E>(vmax));
      vmin = fminf(vmin, fdpp<0xB1>(vmin));         // xor1 quad_perm (VALU)
      vmax = fmaxf(vmax, fdpp<0xB1>(vmax));
      mn = vmin;
      float rng = vmax - vmin + 1e-5f;
      inv   = 255.0f / rng;                         // the only normalize divide
      scale = rng * (1.0f / 255.0f);
    }

    // ---- 3. separable passes chained through register transposes ----

    // pass 1: lane (b,i) reads padded row pr's 8 cols from raw, normalizes
    // (u0..u7), computes a_k = (C * Urow)[k] -> lane holds col i of C*X^T.
    float a0, a1, a2, a3, a4, a5, a6, a7;
    {
      const int pr = ((b >> 1) << 3) + i;          // padded row 0..15
      int sr = pr - 1; sr = sr < 0 ? 0 : (sr > 13 ? 13 : sr);
      const float* rp = raw_ch + sr * 14;
      const int cb = (b & 1) << 3;                 // padded col base 0 or 8
      float u0, u1, u2, u3, u4, u5, u6, u7;
      #define LDU(J, UJ) { int pc_ = cb + (J) - 1; \
                           pc_ = pc_ < 0 ? 0 : (pc_ > 13 ? 13 : pc_); \
                           UJ = fmaf(rp[pc_] - mn, inv, -128.0f); }
      LDU(0, u0) LDU(1, u1) LDU(2, u2) LDU(3, u3)
      LDU(4, u4) LDU(5, u5) LDU(6, u6) LDU(7, u7)
      #undef LDU
      a0 = ROWDOT(0, u0,u1,u2,u3,u4,u5,u6,u7);
      a1 = ROWDOT(1, u0,u1,u2,u3,u4,u5,u6,u7);
      a2 = ROWDOT(2, u0,u1,u2,u3,u4,u5,u6,u7);
      a3 = ROWDOT(3, u0,u1,u2,u3,u4,u5,u6,u7);
      a4 = ROWDOT(4, u0,u1,u2,u3,u4,u5,u6,u7);
      a5 = ROWDOT(5, u0,u1,u2,u3,u4,u5,u6,u7);
      a6 = ROWDOT(6, u0,u1,u2,u3,u4,u5,u6,u7);
      a7 = ROWDOT(7, u0,u1,u2,u3,u4,u5,u6,u7);
    }
    XPOSE8(a0,a1,a2,a3,a4,a5,a6,a7, i)   // lane now holds row i of C*X^T

    // pass 2: D = C*X*C^T (lane holds column i: s_k = D[k][i]), fused quant.
    // s/qv stays an EXACT division: it feeds rintf; round-boundary flips
    // cost up to ~0.08 absmax each — don't trade ulps here.
    float g0, g1, g2, g3, g4, g5, g6, g7;
    #define QUANT(K, QV, DST) { \
      float s_  = ROWDOT(K, a0,a1,a2,a3,a4,a5,a6,a7); \
      float xq_ = s_ / (QV); \
      float r_  = rintf(xq_);            /* round half to even */ \
      float e_  = xq_ - r_; \
      DST = (r_ + e_ * e_ * e_) * (QV); }
    QUANT(0, qv0, g0) QUANT(1, qv1, g1) QUANT(2, qv2, g2) QUANT(3, qv3, g3)
    QUANT(4, qv4, g4) QUANT(5, qv5, g5) QUANT(6, qv6, g6) QUANT(7, qv7, g7)
    #undef QUANT
    // lane holds column i of Qs: g_k = Qs[k][i]

    // pass 3': Z = C^T * Qs computed DIRECTLY from the column-held Qs —
    // z_r = sum_k Qs[k][i]*CM[k][r] = (C^T*Qs)[r][i]. NO transpose needed.
    float z0, z1, z2, z3, z4, z5, z6, z7;
    z0 = COLDOT(0, g0,g1,g2,g3,g4,g5,g6,g7);
    z1 = COLDOT(1, g0,g1,g2,g3,g4,g5,g6,g7);
    z2 = COLDOT(2, g0,g1,g2,g3,g4,g5,g6,g7);
    z3 = COLDOT(3, g0,g1,g2,g3,g4,g5,g6,g7);
    z4 = COLDOT(4, g0,g1,g2,g3,g4,g5,g6,g7);
    z5 = COLDOT(5, g0,g1,g2,g3,g4,g5,g6,g7);
    z6 = COLDOT(6, g0,g1,g2,g3,g4,g5,g6,g7);
    z7 = COLDOT(7, g0,g1,g2,g3,g4,g5,g6,g7);
    XPOSE8(z0,z1,z2,z3,z4,z5,z6,z7, i)   // lane now holds row i of Z

    // pass 4': R row i = (Z*C)[i][:] — out_c = sum_j z_j*CM[j][c]. Fuse
    // crop(1:-1) + (+128) + clip + un-normalize; lane owns padded row
    // prb+i, padded cols cb..cb+7 -> scatter into the natural 14x14 plane
    // over this chunk's dead raw region. 8-lane groups write stride-14
    // rows at a fixed col: banks 14*i mod 32 all distinct; cross-group
    // offsets give <=4-way worst case on 8 write ops — negligible.
    {
      const int cb    = (b & 1) << 3;              // padded col base 0 or 8
      const int prb   = (b >> 1) << 3;             // padded row base 0 or 8
      const int pr    = prb + i;                   // this lane's padded row
      const bool prv  = (pr >= 1) && (pr <= 14);
      const int rowoff = (pr - 1) * 14;            // guarded by prv
      float* crop = rawp + chl * HW;
      #define OUTK(K) { \
        float s_ = COLDOT(K, z0,z1,z2,z3,z4,z5,z6,z7); \
        const int col_ = cb + (K) - 1; \
        if (prv && col_ >= 0 && col_ <= 13) { \
          float v_ = fminf(fmaxf(s_ + 128.0f, 0.0f), 255.0f); \
          crop[rowoff + col_] = fmaf(v_, scale, mn); } }
      OUTK(0) OUTK(1) OUTK(2) OUTK(3) OUTK(4) OUTK(5) OUTK(6) OUTK(7)
      #undef OUTK
    }
    WAVE_LDS_SYNC();   // plane writes land before the cross-lane copy reads

    // ---- 4. pure vectorized copy: LDS plane -> global (coalesced f4) ----
    {
      const float4* src = (const float4*)rawp;
      float4* o4 = (float4*)out + (c0 + p) * (CHUNK_F / 4) + w * (CPW / 4);
      o4[wl] = src[wl];                            // f4 0..63
      if (wl < CPW / 4 - 64)                       // lanes 0..33: f4 64..97
        o4[64 + wl] = src[64 + wl];
    }
  }
}

extern "C" void kernel_launch(void* const* d_in, const int* in_sizes, int n_in,
                              void* d_out, int out_size, void* d_ws, size_t ws_size,
                              hipStream_t stream) {
  const float* x = (const float*)d_in[0];
  float* out     = (float*)d_out;
  const int ntot   = in_sizes[0];                   // 32*1024*14*14
  const int nch    = ntot / HW;                     // 32768 channels
  const int chunks = (nch + CH_PER_WG - 1) / CH_PER_WG;  // 4096
  const int grid   = (chunks + 1) / 2;              // 2048 blocks, 2 chunks each
  hipLaunchKernelGGL(jpeg_codec_kernel, dim3(grid), dim3(256), 0, stream,
                     x, out);
}

// Round 7
// 83.936 us; speedup vs baseline: 1.0235x; 1.0235x over previous
//
#include <hip/hip_runtime.h>

// JPEG-compression-as-augmentation, collapsed to luma-only per-channel codec.
// Chroma planes of a gray (v,v,v) image are exactly 128 and the chroma codec
// is an exact fixed point, so only the Y path survives. Per (B,C) channel:
//   min/max normalize -> *255 -> edge-pad 14x14 -> 16x16 -> 4 blocks of 8x8
//   R = C^T * diffround( C*(X-128)*C^T / (Y_T*f) ) * (Y_T*f) * C + 128
//   out = clip(R,0,255)/255 * rng + min        (f = 0.02 at quality 99)
//
// Round-11: FULL OCCUPANCY for the named-scalar kernel. Attribution:
//  * Kernel-only times (total minus the invariant ~62us harness overhead):
//    round-5 LDS ping-pong lb(256,8) = ~19.4us; round-9 register/fence-free
//    lb(256,4) = ~22.7; round-10 (-35 DS ops) = ~23.9. Fence removal AND
//    DS-op halving both produced NO gain -> DS-pipe theory refuted. The
//    distinguishing variable is occupancy: round-5 ran 32 waves/CU; the
//    register versions' ~50-reg working set under lb(256,4) lands in the
//    65-128 VGPR bin -> 16 waves/CU + two dispatch generations.
//  * This round: lb(256,8) (64-VGPR budget). NOT a round-6 rerun: round-8
//    proved that spill was SROA failure on float[8] arrays (VGPR pinned at
//    32 under ANY budget); round-9's named scalars fixed promotion. Peak
//    live state ~45-55 regs -> fits 64. Tripwire: if it spills, kernel
//    shows at ~80us in top-5 / total ~141 -> revert to round-5 source.
//  * 1 chunk per block, 4096 blocks (round-5 grid, measured fastest; the
//    2-deep pipeline never showed a gain). No chunk loop at all -> the
//    round-7 "#pragma unroll 1" miscompile class is structurally gone.
//  * Kept from round-10 (free wins): z-direct IDCT (Z = C^T*Qs straight
//    from column-held Qs; 2 transposes not 3), row-held output scatter.
//    Plain __shfl_xor transposes (round-10's DPP+selects measured no
//    better).
// Retained: global_load_lds width-16 staging, single vmcnt + single lgkm
// fence, no s_barrier anywhere, transposed prescaled quant table (2
// float4/lane), EXACT fp32 quant divide (round-boundary sensitive - do not
// trade ulps), float4 global I/O.

namespace {

constexpr int CH_PER_WG = 8;       // 4 waves * 2 channels
constexpr int HW        = 196;     // 14*14
constexpr int CPW       = 2 * HW;  // floats per wave (2 channels)
constexpr int CHUNK_F   = CH_PER_WG * HW;  // 1568 floats per block

// Orthonormal 8-point DCT-II matrix: CM[u][x] = 0.5*alpha_u*cos((2x+1)u*pi/16).
// Only ever indexed with compile-time literals -> folds to inline constants.
constexpr float CM[8][8] = {
  { 0.35355339059327376f,  0.35355339059327376f,  0.35355339059327376f,  0.35355339059327376f,
    0.35355339059327376f,  0.35355339059327376f,  0.35355339059327376f,  0.35355339059327376f},
  { 0.49039264020161522f,  0.41573480615127262f,  0.27778511650980114f,  0.09754516100806417f,
   -0.09754516100806417f, -0.27778511650980114f, -0.41573480615127262f, -0.49039264020161522f},
  { 0.46193976625564337f,  0.19134171618254492f, -0.19134171618254492f, -0.46193976625564337f,
   -0.46193976625564337f, -0.19134171618254492f,  0.19134171618254492f,  0.46193976625564337f},
  { 0.41573480615127262f, -0.09754516100806417f, -0.49039264020161522f, -0.27778511650980114f,
    0.27778511650980114f,  0.49039264020161522f,  0.09754516100806417f, -0.41573480615127262f},
  { 0.35355339059327376f, -0.35355339059327376f, -0.35355339059327376f,  0.35355339059327376f,
    0.35355339059327376f, -0.35355339059327376f, -0.35355339059327376f,  0.35355339059327376f},
  { 0.27778511650980114f, -0.49039264020161522f,  0.09754516100806417f,  0.41573480615127262f,
   -0.41573480615127262f, -0.09754516100806417f,  0.49039264020161522f, -0.27778511650980114f},
  { 0.19134171618254492f, -0.46193976625564337f,  0.46193976625564337f, -0.19134171618254492f,
   -0.19134171618254492f,  0.46193976625564337f, -0.46193976625564337f,  0.19134171618254492f},
  { 0.09754516100806417f, -0.27778511650980114f,  0.41573480615127262f, -0.49039264020161522f,
    0.49039264020161522f, -0.41573480615127262f,  0.27778511650980114f, -0.09754516100806417f},
};

} // namespace

// Transposed, pre-scaled luma quant table: QVT[i][k] = Y_T[k][i] * 0.02f.
// int*0.02f is constant-folded in IEEE fp32 RN -> bit-identical to the
// runtime v_mul of earlier rounds. Row i is 16B-aligned: one lane reads its
// whole column as two float4 while the staging DMA is in flight.
#define SF 0.02f
__device__ __align__(16) const float QVT[8][8] = {
  {16*SF, 12*SF, 14*SF, 14*SF, 18*SF,  24*SF,  49*SF,  72*SF},
  {11*SF, 12*SF, 13*SF, 17*SF, 22*SF,  35*SF,  64*SF,  92*SF},
  {10*SF, 14*SF, 16*SF, 22*SF, 37*SF,  55*SF,  78*SF,  95*SF},
  {16*SF, 19*SF, 24*SF, 29*SF, 56*SF,  64*SF,  87*SF,  98*SF},
  {24*SF, 26*SF, 40*SF, 51*SF, 68*SF,  81*SF, 103*SF, 112*SF},
  {40*SF, 58*SF, 57*SF, 87*SF, 109*SF, 104*SF, 121*SF, 100*SF},
  {51*SF, 60*SF, 69*SF, 80*SF, 103*SF, 113*SF, 120*SF, 103*SF},
  {61*SF, 55*SF, 56*SF, 62*SF, 77*SF,  92*SF, 101*SF,  99*SF},
};
#undef SF

// Intra-wave fences. All producers and consumers of any LDS/VMEM data are in
// the same wave, so no s_barrier exists anywhere in the kernel.
#define WAVE_LDS_SYNC() asm volatile("s_waitcnt lgkmcnt(0)" ::: "memory")
#define WAVE_VM_SYNC()  asm volatile("s_waitcnt vmcnt(0)" ::: "memory")

typedef __attribute__((address_space(1))) const void gvoid_t;
typedef __attribute__((address_space(3))) void       lvoid_t;

// Dot products as explicit fmaf chains, SAME nesting order as the original
// "s=0; for j: s=fmaf(x[j],C,s)" loop -> bit-identical results.
// ROWDOT: sum_j x_j * CM[K][j]   COLDOT: sum_j x_j * CM[j][K]
#define ROWDOT(K, x0,x1,x2,x3,x4,x5,x6,x7) \
  fmaf(x7, CM[K][7], fmaf(x6, CM[K][6], fmaf(x5, CM[K][5], fmaf(x4, CM[K][4], \
  fmaf(x3, CM[K][3], fmaf(x2, CM[K][2], fmaf(x1, CM[K][1], fmaf(x0, CM[K][0], 0.0f))))))))
#define COLDOT(K, x0,x1,x2,x3,x4,x5,x6,x7) \
  fmaf(x7, CM[7][K], fmaf(x6, CM[6][K], fmaf(x5, CM[5][K], fmaf(x4, CM[4][K], \
  fmaf(x3, CM[3][K], fmaf(x2, CM[2][K], fmaf(x1, CM[1][K], fmaf(x0, CM[0][K], 0.0f))))))))

// One butterfly step of the exact 8x8 lane-group transpose, on NAMED
// scalars (pure selects, no memory). up lane ((i&d)==0) exchanges its B
// with the partner's A. Pure data movement -> bit-identical.
#define XST(D, A, B) { float snd_ = upd_ ? (B) : (A); \
                       float got_ = __shfl_xor(snd_, (D), 64); \
                       (A) = upd_ ? (A) : got_; \
                       (B) = upd_ ? got_ : (B); }

// Full transpose: element (reg r, lane l) -> (reg l, lane r) within each
// 8-lane group. Stages d=1,2,4.
#define XPOSE8(x0,x1,x2,x3,x4,x5,x6,x7, LANE) { \
  { const bool upd_ = ((LANE) & 1) == 0; \
    XST(1, x0, x1) XST(1, x2, x3) XST(1, x4, x5) XST(1, x6, x7) } \
  { const bool upd_ = ((LANE) & 2) == 0; \
    XST(2, x0, x2) XST(2, x1, x3) XST(2, x4, x6) XST(2, x5, x7) } \
  { const bool upd_ = ((LANE) & 4) == 0; \
    XST(4, x0, x4) XST(4, x1, x5) XST(4, x2, x6) XST(4, x3, x7) } }

__global__ __launch_bounds__(256, 8)
void jpeg_codec_kernel(const float* __restrict__ x, float* __restrict__ out) {
  // Single raw staging buffer; the output plane reuses it (raw is dead
  // after pass 1; same-wave DS ops are processed in order). 6272 B/block
  // -> LDS allows far more than the 8 blocks/CU the thread limit gives.
  __shared__ __align__(16) float s_raw[4 * CPW];

  const int tid = threadIdx.x;
  const int w   = tid >> 6;       // wave 0..3
  const int wl  = tid & 63;       // lane in wave
  const int chl = (tid >> 5) & 1; // channel-in-wave 0/1
  const int l   = tid & 31;       // lane-in-channel
  const int b   = l >> 3;         // block 0..3
  const int i   = l & 7;          // row/col 0..7

  // wave w owns global float4 range [g4, g4+98) = 2 channels of 49 f4 each
  const long long g4 = (long long)blockIdx.x * (CHUNK_F / 4) + w * (CPW / 4);

  // ---- 1. per-wave async staging: raw -> s_raw[w*CPW .. +392) ----
  // global_load_lds writes lane j's 16B to (uniform lds base) + j*16 — the
  // contiguous layout we want.
  {
    const float4* x4 = (const float4*)x + g4;
    float* raw = s_raw + w * CPW;
    __builtin_amdgcn_global_load_lds((gvoid_t*)(x4 + wl), (lvoid_t*)raw, 16, 0, 0);
    if (wl < CPW / 4 - 64)  // lanes 0..33 stage f4 64..97
      __builtin_amdgcn_global_load_lds((gvoid_t*)(x4 + 64 + wl),
                                       (lvoid_t*)(raw + 256), 16, 0, 0);
  }

  // per-lane quant column as NAMED scalars, loaded while DMA is in flight
  float qv0, qv1, qv2, qv3, qv4, qv5, qv6, qv7;
  {
    const float4* qt = (const float4*)QVT[i];
    float4 qa = qt[0], qb = qt[1];
    qv0 = qa.x; qv1 = qa.y; qv2 = qa.z; qv3 = qa.w;
    qv4 = qb.x; qv5 = qb.y; qv6 = qb.z; qv7 = qb.w;
  }

  WAVE_VM_SYNC();

  float* rawp = s_raw + w * CPW;
  const float* raw_ch = rawp + chl * HW;  // this lane's channel raw

  // ---- 2. per-channel min/max: float4 reads + shuffle butterfly ----
  float mn, inv, scale;          // uniform within the 32-lane channel group
  {
    float vmin = 1e30f, vmax = -1e30f;
    const float4* c4 = (const float4*)raw_ch;       // offsets %16 == 0
    {
      float4 v = c4[l];                             // f4 0..31
      vmin = fminf(fminf(vmin, v.x), fminf(v.y, fminf(v.z, v.w)));
      vmax = fmaxf(fmaxf(vmax, v.x), fmaxf(v.y, fmaxf(v.z, v.w)));
    }
    if (l < 17) {                                   // f4 32..48
      float4 v = c4[l + 32];
      vmin = fminf(fminf(vmin, v.x), fminf(v.y, fminf(v.z, v.w)));
      vmax = fmaxf(fmaxf(vmax, v.x), fmaxf(v.y, fmaxf(v.z, v.w)));
    }
    #pragma unroll
    for (int off = 16; off; off >>= 1) {            // xor<=16 stays in 32-group
      vmin = fminf(vmin, __shfl_xor(vmin, off, 64));
      vmax = fmaxf(vmax, __shfl_xor(vmax, off, 64));
    }
    mn = vmin;
    float rng = vmax - vmin + 1e-5f;
    inv   = 255.0f / rng;                           // the only normalize divide
    scale = rng * (1.0f / 255.0f);
  }

  // ---- 3. separable passes chained through register transposes ----

  // pass 1: lane (b,i) reads padded row pr's 8 cols from raw, normalizes
  // (u0..u7), computes a_k = (C * Urow)[k] -> lane holds col i of C*X^T.
  float a0, a1, a2, a3, a4, a5, a6, a7;
  {
    const int pr = ((b >> 1) << 3) + i;            // padded row 0..15
    int sr = pr - 1; sr = sr < 0 ? 0 : (sr > 13 ? 13 : sr);
    const float* rp = raw_ch + sr * 14;
    const int cb = (b & 1) << 3;                   // padded col base 0 or 8
    float u0, u1, u2, u3, u4, u5, u6, u7;
    #define LDU(J, UJ) { int pc_ = cb + (J) - 1; \
                         pc_ = pc_ < 0 ? 0 : (pc_ > 13 ? 13 : pc_); \
                         UJ = fmaf(rp[pc_] - mn, inv, -128.0f); }
    LDU(0, u0) LDU(1, u1) LDU(2, u2) LDU(3, u3)
    LDU(4, u4) LDU(5, u5) LDU(6, u6) LDU(7, u7)
    #undef LDU
    a0 = ROWDOT(0, u0,u1,u2,u3,u4,u5,u6,u7);
    a1 = ROWDOT(1, u0,u1,u2,u3,u4,u5,u6,u7);
    a2 = ROWDOT(2, u0,u1,u2,u3,u4,u5,u6,u7);
    a3 = ROWDOT(3, u0,u1,u2,u3,u4,u5,u6,u7);
    a4 = ROWDOT(4, u0,u1,u2,u3,u4,u5,u6,u7);
    a5 = ROWDOT(5, u0,u1,u2,u3,u4,u5,u6,u7);
    a6 = ROWDOT(6, u0,u1,u2,u3,u4,u5,u6,u7);
    a7 = ROWDOT(7, u0,u1,u2,u3,u4,u5,u6,u7);
  }
  XPOSE8(a0,a1,a2,a3,a4,a5,a6,a7, i)   // lane now holds row i of C*X^T

  // pass 2: D = C*X*C^T (lane holds column i: s_k = D[k][i]), fused quant.
  // s/qv stays an EXACT division: it feeds rintf; round-boundary flips
  // cost up to ~0.08 absmax each — don't trade ulps here.
  float g0, g1, g2, g3, g4g, g5, g6, g7;
  #define QUANT(K, QV, DST) { \
    float s_  = ROWDOT(K, a0,a1,a2,a3,a4,a5,a6,a7); \
    float xq_ = s_ / (QV); \
    float r_  = rintf(xq_);            /* round half to even */ \
    float e_  = xq_ - r_; \
    DST = (r_ + e_ * e_ * e_) * (QV); }
  QUANT(0, qv0, g0) QUANT(1, qv1, g1) QUANT(2, qv2, g2) QUANT(3, qv3, g3)
  QUANT(4, qv4, g4g) QUANT(5, qv5, g5) QUANT(6, qv6, g6) QUANT(7, qv7, g7)
  #undef QUANT
  // lane holds column i of Qs: g_k = Qs[k][i]

  // pass 3': Z = C^T * Qs computed DIRECTLY from the column-held Qs —
  // z_r = sum_k Qs[k][i]*CM[k][r] = (C^T*Qs)[r][i]. NO transpose needed.
  float z0, z1, z2, z3, z4, z5, z6, z7;
  z0 = COLDOT(0, g0,g1,g2,g3,g4g,g5,g6,g7);
  z1 = COLDOT(1, g0,g1,g2,g3,g4g,g5,g6,g7);
  z2 = COLDOT(2, g0,g1,g2,g3,g4g,g5,g6,g7);
  z3 = COLDOT(3, g0,g1,g2,g3,g4g,g5,g6,g7);
  z4 = COLDOT(4, g0,g1,g2,g3,g4g,g5,g6,g7);
  z5 = COLDOT(5, g0,g1,g2,g3,g4g,g5,g6,g7);
  z6 = COLDOT(6, g0,g1,g2,g3,g4g,g5,g6,g7);
  z7 = COLDOT(7, g0,g1,g2,g3,g4g,g5,g6,g7);
  XPOSE8(z0,z1,z2,z3,z4,z5,z6,z7, i)   // lane now holds row i of Z

  // pass 4': R row i = (Z*C)[i][:] — out_c = sum_j z_j*CM[j][c]. Fuse
  // crop(1:-1) + (+128) + clip + un-normalize; lane owns padded row prb+i,
  // padded cols cb..cb+7 -> scatter into the natural 14x14 plane over this
  // wave's dead raw region (raw fully consumed; same-wave DS ops are
  // processed in order so earlier reads complete before these writes).
  {
    const int cb     = (b & 1) << 3;               // padded col base 0 or 8
    const int prb    = (b >> 1) << 3;              // padded row base 0 or 8
    const int pr     = prb + i;                    // this lane's padded row
    const bool prv   = (pr >= 1) && (pr <= 14);
    const int rowoff = (pr - 1) * 14;              // guarded by prv
    float* crop = rawp + chl * HW;
    #define OUTK(K) { \
      float s_ = COLDOT(K, z0,z1,z2,z3,z4,z5,z6,z7); \
      const int col_ = cb + (K) - 1; \
      if (prv && col_ >= 0 && col_ <= 13) { \
        float v_ = fminf(fmaxf(s_ + 128.0f, 0.0f), 255.0f); \
        crop[rowoff + col_] = fmaf(v_, scale, mn); } }
    OUTK(0) OUTK(1) OUTK(2) OUTK(3) OUTK(4) OUTK(5) OUTK(6) OUTK(7)
    #undef OUTK
  }
  WAVE_LDS_SYNC();   // plane writes land before the cross-lane copy reads

  // ---- 4. pure vectorized copy: LDS plane -> global (coalesced f4) ----
  {
    const float4* src = (const float4*)rawp;
    float4* o4 = (float4*)out + g4;
    o4[wl] = src[wl];                              // f4 0..63
    if (wl < CPW / 4 - 64)                         // lanes 0..33: f4 64..97
      o4[64 + wl] = src[64 + wl];
  }
}

extern "C" void kernel_launch(void* const* d_in, const int* in_sizes, int n_in,
                              void* d_out, int out_size, void* d_ws, size_t ws_size,
                              hipStream_t stream) {
  const float* x = (const float*)d_in[0];
  float* out     = (float*)d_out;
  const int ntot = in_sizes[0];                       // 32*1024*14*14
  const int nch  = ntot / HW;                         // 32768 channels
  const int grid = (nch + CH_PER_WG - 1) / CH_PER_WG; // 4096 workgroups
  hipLaunchKernelGGL(jpeg_codec_kernel, dim3(grid), dim3(256), 0, stream,
                     x, out);
}

// Round 8
// 82.788 us; speedup vs baseline: 1.0377x; 1.0139x over previous
//
#include <hip/hip_runtime.h>

// JPEG-compression-as-augmentation, collapsed to luma-only per-channel codec.
// Chroma planes of a gray (v,v,v) image are exactly 128 and the chroma codec
// is an exact fixed point, so only the Y path survives. Per (B,C) channel:
//   min/max normalize -> *255 -> edge-pad 14x14 -> 16x16 -> 4 blocks of 8x8
//   R = C^T * diffround( C*(X-128)*C^T / (Y_T*f) ) * (Y_T*f) * C + 128
//   out = clip(R,0,255)/255 * rng + min        (f = 0.02 at quality 99)
//
// Round-12: ZERO-LDS kernel. Attribution ledger (kernel-only = total minus
// the invariant ~61.5us harness overhead, anchored by rounds 2/4):
//   r5 LDS ping-pong 19.9 | r9 reg+fences-gone 23.3 | r10 -35 DS ops 24.5 |
//   r11 reg+full-occupancy 22.4. Fence-removal, DS-op-halving and occupancy
//   theories ALL null. The untested axis is the LDS stage itself: every
//   variant so far serializes each wave on a cold-HBM vmcnt(0) drain into
//   LDS and a lgkmcnt(0) output bounce. This round: registers only.
//  * min/max float4 loads come DIRECTLY from global (coalesced, same guard).
//  * pass-1 row reads come directly from global: the wave's 1.5KB working
//    set was just fetched by the minmax loads; 16 waves/CU x 1.5KB = 25KB
//    fits L1 (32KB/CU) -> these are L1 hits.
//  * pass-4 stores the cropped pixels directly to global (7 scalar stores
//    per lane into the wave-contiguous 1.5KB region; L2 merges full lines,
//    total write bytes unchanged at ~26MB).
//  * No __shared__, no s_waitcnt asm, no barrier. Compiler inserts its own
//    waitcnts before uses.
// Bit-identical arithmetic to r11 (same ROWDOT/QUANT/COLDOT/XPOSE8 chain,
// same order) -> absmax must stay exactly 0.015625.
// Pre-committed read: 76-80us => LDS/fence latency was the cost; flat >=82
// => ~20us kernel is the launch+latency floor behind the 44us poison fill
// -> declare roofline next round. Tripwire: FETCH_SIZE >> 26MB = L1 thrash
// -> revert to round-5 source as final.
// Attribution history kept: r7 "#pragma unroll 1" => WRONG RESULTS (no
// runtime-trip-count loops here at all); r8: float[8] locals are never
// SROA-promoted -> NAMED SCALARS mandatory; r6/r11: lb(256,8) is safe with
// named scalars (no spill), only arrays spilled.

namespace {

constexpr int CH_PER_WG = 8;       // 4 waves * 2 channels
constexpr int HW        = 196;     // 14*14

// Orthonormal 8-point DCT-II matrix: CM[u][x] = 0.5*alpha_u*cos((2x+1)u*pi/16).
// Only ever indexed with compile-time literals -> folds to inline constants.
constexpr float CM[8][8] = {
  { 0.35355339059327376f,  0.35355339059327376f,  0.35355339059327376f,  0.35355339059327376f,
    0.35355339059327376f,  0.35355339059327376f,  0.35355339059327376f,  0.35355339059327376f},
  { 0.49039264020161522f,  0.41573480615127262f,  0.27778511650980114f,  0.09754516100806417f,
   -0.09754516100806417f, -0.27778511650980114f, -0.41573480615127262f, -0.49039264020161522f},
  { 0.46193976625564337f,  0.19134171618254492f, -0.19134171618254492f, -0.46193976625564337f,
   -0.46193976625564337f, -0.19134171618254492f,  0.19134171618254492f,  0.46193976625564337f},
  { 0.41573480615127262f, -0.09754516100806417f, -0.49039264020161522f, -0.27778511650980114f,
    0.27778511650980114f,  0.49039264020161522f,  0.09754516100806417f, -0.41573480615127262f},
  { 0.35355339059327376f, -0.35355339059327376f, -0.35355339059327376f,  0.35355339059327376f,
    0.35355339059327376f, -0.35355339059327376f, -0.35355339059327376f,  0.35355339059327376f},
  { 0.27778511650980114f, -0.49039264020161522f,  0.09754516100806417f,  0.41573480615127262f,
   -0.41573480615127262f, -0.09754516100806417f,  0.49039264020161522f, -0.27778511650980114f},
  { 0.19134171618254492f, -0.46193976625564337f,  0.46193976625564337f, -0.19134171618254492f,
   -0.19134171618254492f,  0.46193976625564337f, -0.46193976625564337f,  0.19134171618254492f},
  { 0.09754516100806417f, -0.27778511650980114f,  0.41573480615127262f, -0.49039264020161522f,
    0.49039264020161522f, -0.41573480615127262f,  0.27778511650980114f, -0.09754516100806417f},
};

} // namespace

// Transposed, pre-scaled luma quant table: QVT[i][k] = Y_T[k][i] * 0.02f.
// int*0.02f is constant-folded in IEEE fp32 RN -> bit-identical to the
// runtime v_mul of earlier rounds. Row i is 16B-aligned: one lane reads its
// whole column as two float4.
#define SF 0.02f
__device__ __align__(16) const float QVT[8][8] = {
  {16*SF, 12*SF, 14*SF, 14*SF, 18*SF,  24*SF,  49*SF,  72*SF},
  {11*SF, 12*SF, 13*SF, 17*SF, 22*SF,  35*SF,  64*SF,  92*SF},
  {10*SF, 14*SF, 16*SF, 22*SF, 37*SF,  55*SF,  78*SF,  95*SF},
  {16*SF, 19*SF, 24*SF, 29*SF, 56*SF,  64*SF,  87*SF,  98*SF},
  {24*SF, 26*SF, 40*SF, 51*SF, 68*SF,  81*SF, 103*SF, 112*SF},
  {40*SF, 58*SF, 57*SF, 87*SF, 109*SF, 104*SF, 121*SF, 100*SF},
  {51*SF, 60*SF, 69*SF, 80*SF, 103*SF, 113*SF, 120*SF, 103*SF},
  {61*SF, 55*SF, 56*SF, 62*SF, 77*SF,  92*SF, 101*SF,  99*SF},
};
#undef SF

// Dot products as explicit fmaf chains, SAME nesting order as the original
// "s=0; for j: s=fmaf(x[j],C,s)" loop -> bit-identical results.
// ROWDOT: sum_j x_j * CM[K][j]   COLDOT: sum_j x_j * CM[j][K]
#define ROWDOT(K, x0,x1,x2,x3,x4,x5,x6,x7) \
  fmaf(x7, CM[K][7], fmaf(x6, CM[K][6], fmaf(x5, CM[K][5], fmaf(x4, CM[K][4], \
  fmaf(x3, CM[K][3], fmaf(x2, CM[K][2], fmaf(x1, CM[K][1], fmaf(x0, CM[K][0], 0.0f))))))))
#define COLDOT(K, x0,x1,x2,x3,x4,x5,x6,x7) \
  fmaf(x7, CM[7][K], fmaf(x6, CM[6][K], fmaf(x5, CM[5][K], fmaf(x4, CM[4][K], \
  fmaf(x3, CM[3][K], fmaf(x2, CM[2][K], fmaf(x1, CM[1][K], fmaf(x0, CM[0][K], 0.0f))))))))

// One butterfly step of the exact 8x8 lane-group transpose, on NAMED
// scalars (pure selects, no memory). up lane ((i&d)==0) exchanges its B
// with the partner's A. Pure data movement -> bit-identical.
#define XST(D, A, B) { float snd_ = upd_ ? (B) : (A); \
                       float got_ = __shfl_xor(snd_, (D), 64); \
                       (A) = upd_ ? (A) : got_; \
                       (B) = upd_ ? got_ : (B); }

// Full transpose: element (reg r, lane l) -> (reg l, lane r) within each
// 8-lane group. Stages d=1,2,4.
#define XPOSE8(x0,x1,x2,x3,x4,x5,x6,x7, LANE) { \
  { const bool upd_ = ((LANE) & 1) == 0; \
    XST(1, x0, x1) XST(1, x2, x3) XST(1, x4, x5) XST(1, x6, x7) } \
  { const bool upd_ = ((LANE) & 2) == 0; \
    XST(2, x0, x2) XST(2, x1, x3) XST(2, x4, x6) XST(2, x5, x7) } \
  { const bool upd_ = ((LANE) & 4) == 0; \
    XST(4, x0, x4) XST(4, x1, x5) XST(4, x2, x6) XST(4, x3, x7) } }

__global__ __launch_bounds__(256, 8)
void jpeg_codec_kernel(const float* __restrict__ x, float* __restrict__ out) {
  const int tid = threadIdx.x;
  const int w   = tid >> 6;       // wave 0..3
  const int chl = (tid >> 5) & 1; // channel-in-wave 0/1
  const int l   = tid & 31;       // lane-in-channel
  const int b   = l >> 3;         // block 0..3
  const int i   = l & 7;          // row/col 0..7

  // this lane's channel (196 floats, 16B-aligned: base offsets are x784B)
  const long long chF = ((long long)blockIdx.x * CH_PER_WG + w * 2 + chl) * HW;
  const float* xch = x + chF;
  float*       och = out + chF;

  // per-lane quant column as NAMED scalars (L2-broadcast)
  float qv0, qv1, qv2, qv3, qv4, qv5, qv6, qv7;
  {
    const float4* qt = (const float4*)QVT[i];
    float4 qa = qt[0], qb = qt[1];
    qv0 = qa.x; qv1 = qa.y; qv2 = qa.z; qv3 = qa.w;
    qv4 = qb.x; qv5 = qb.y; qv6 = qb.z; qv7 = qb.w;
  }

  // ---- 1. per-channel min/max: coalesced float4 global reads + butterfly ----
  float mn, inv, scale;          // uniform within the 32-lane channel group
  {
    float vmin = 1e30f, vmax = -1e30f;
    const float4* c4 = (const float4*)xch;          // 49 f4 per channel
    {
      float4 v = c4[l];                             // f4 0..31
      vmin = fminf(fminf(vmin, v.x), fminf(v.y, fminf(v.z, v.w)));
      vmax = fmaxf(fmaxf(vmax, v.x), fmaxf(v.y, fmaxf(v.z, v.w)));
    }
    if (l < 17) {                                   // f4 32..48
      float4 v = c4[l + 32];
      vmin = fminf(fminf(vmin, v.x), fminf(v.y, fminf(v.z, v.w)));
      vmax = fmaxf(fmaxf(vmax, v.x), fmaxf(v.y, fmaxf(v.z, v.w)));
    }
    #pragma unroll
    for (int off = 16; off; off >>= 1) {            // xor<=16 stays in 32-group
      vmin = fminf(vmin, __shfl_xor(vmin, off, 64));
      vmax = fmaxf(vmax, __shfl_xor(vmax, off, 64));
    }
    mn = vmin;
    float rng = vmax - vmin + 1e-5f;
    inv   = 255.0f / rng;                           // the only normalize divide
    scale = rng * (1.0f / 255.0f);
  }

  // ---- 2. separable passes chained through register transposes ----

  // pass 1: lane (b,i) reads padded row pr's 8 cols DIRECTLY from global
  // (L1-hot: the minmax loads just fetched this wave's 1.5KB), normalizes
  // (u0..u7), computes a_k = (C * Urow)[k] -> lane holds col i of C*X^T.
  float a0, a1, a2, a3, a4, a5, a6, a7;
  {
    const int pr = ((b >> 1) << 3) + i;            // padded row 0..15
    int sr = pr - 1; sr = sr < 0 ? 0 : (sr > 13 ? 13 : sr);
    const float* rp = xch + sr * 14;
    const int cb = (b & 1) << 3;                   // padded col base 0 or 8
    float u0, u1, u2, u3, u4, u5, u6, u7;
    #define LDU(J, UJ) { int pc_ = cb + (J) - 1; \
                         pc_ = pc_ < 0 ? 0 : (pc_ > 13 ? 13 : pc_); \
                         UJ = fmaf(rp[pc_] - mn, inv, -128.0f); }
    LDU(0, u0) LDU(1, u1) LDU(2, u2) LDU(3, u3)
    LDU(4, u4) LDU(5, u5) LDU(6, u6) LDU(7, u7)
    #undef LDU
    a0 = ROWDOT(0, u0,u1,u2,u3,u4,u5,u6,u7);
    a1 = ROWDOT(1, u0,u1,u2,u3,u4,u5,u6,u7);
    a2 = ROWDOT(2, u0,u1,u2,u3,u4,u5,u6,u7);
    a3 = ROWDOT(3, u0,u1,u2,u3,u4,u5,u6,u7);
    a4 = ROWDOT(4, u0,u1,u2,u3,u4,u5,u6,u7);
    a5 = ROWDOT(5, u0,u1,u2,u3,u4,u5,u6,u7);
    a6 = ROWDOT(6, u0,u1,u2,u3,u4,u5,u6,u7);
    a7 = ROWDOT(7, u0,u1,u2,u3,u4,u5,u6,u7);
  }
  XPOSE8(a0,a1,a2,a3,a4,a5,a6,a7, i)   // lane now holds row i of C*X^T

  // pass 2: D = C*X*C^T (lane holds column i: s_k = D[k][i]), fused quant.
  // s/qv stays an EXACT division: it feeds rintf; round-boundary flips
  // cost up to ~0.08 absmax each — don't trade ulps here.
  float g0, g1, g2, g3, g4g, g5, g6, g7;
  #define QUANT(K, QV, DST) { \
    float s_  = ROWDOT(K, a0,a1,a2,a3,a4,a5,a6,a7); \
    float xq_ = s_ / (QV); \
    float r_  = rintf(xq_);            /* round half to even */ \
    float e_  = xq_ - r_; \
    DST = (r_ + e_ * e_ * e_) * (QV); }
  QUANT(0, qv0, g0) QUANT(1, qv1, g1) QUANT(2, qv2, g2) QUANT(3, qv3, g3)
  QUANT(4, qv4, g4g) QUANT(5, qv5, g5) QUANT(6, qv6, g6) QUANT(7, qv7, g7)
  #undef QUANT
  // lane holds column i of Qs: g_k = Qs[k][i]

  // pass 3': Z = C^T * Qs computed DIRECTLY from the column-held Qs —
  // z_r = sum_k Qs[k][i]*CM[k][r] = (C^T*Qs)[r][i]. NO transpose needed.
  float z0, z1, z2, z3, z4, z5, z6, z7;
  z0 = COLDOT(0, g0,g1,g2,g3,g4g,g5,g6,g7);
  z1 = COLDOT(1, g0,g1,g2,g3,g4g,g5,g6,g7);
  z2 = COLDOT(2, g0,g1,g2,g3,g4g,g5,g6,g7);
  z3 = COLDOT(3, g0,g1,g2,g3,g4g,g5,g6,g7);
  z4 = COLDOT(4, g0,g1,g2,g3,g4g,g5,g6,g7);
  z5 = COLDOT(5, g0,g1,g2,g3,g4g,g5,g6,g7);
  z6 = COLDOT(6, g0,g1,g2,g3,g4g,g5,g6,g7);
  z7 = COLDOT(7, g0,g1,g2,g3,g4g,g5,g6,g7);
  XPOSE8(z0,z1,z2,z3,z4,z5,z6,z7, i)   // lane now holds row i of Z

  // pass 4': R row i = (Z*C)[i][:] — out_c = sum_j z_j*CM[j][c]. Fuse
  // crop(1:-1) + (+128) + clip + un-normalize; lane owns padded row prb+i,
  // padded cols cb..cb+7 -> store the <=7 valid cropped pixels DIRECTLY to
  // global (wave-contiguous 1.5KB region; L2 merges full lines, write
  // bytes unchanged). Each output pixel is written exactly once across the
  // four (b) blocks: rows 0..6 from prb=0 (i=1..7), rows 7..13 from prb=8
  // (i=0..6); cols 0..6 from b even, 7..13 from b odd.
  {
    const int cb  = (b & 1) << 3;                  // padded col base 0 or 8
    const int prb = (b >> 1) << 3;                 // padded row base 0 or 8
    const int pr  = prb + i;                       // this lane's padded row
    if (pr >= 1 && pr <= 14) {
      float* orow = och + (pr - 1) * 14;
      #define OUTK(K) { \
        float s_ = COLDOT(K, z0,z1,z2,z3,z4,z5,z6,z7); \
        const int col_ = cb + (K) - 1; \
        if (col_ >= 0 && col_ <= 13) { \
          float v_ = fminf(fmaxf(s_ + 128.0f, 0.0f), 255.0f); \
          orow[col_] = fmaf(v_, scale, mn); } }
      OUTK(0) OUTK(1) OUTK(2) OUTK(3) OUTK(4) OUTK(5) OUTK(6) OUTK(7)
      #undef OUTK
    }
  }
}

extern "C" void kernel_launch(void* const* d_in, const int* in_sizes, int n_in,
                              void* d_out, int out_size, void* d_ws, size_t ws_size,
                              hipStream_t stream) {
  const float* x = (const float*)d_in[0];
  float* out     = (float*)d_out;
  const int ntot = in_sizes[0];                       // 32*1024*14*14
  const int nch  = ntot / HW;                         // 32768 channels
  const int grid = (nch + CH_PER_WG - 1) / CH_PER_WG; // 4096 workgroups
  hipLaunchKernelGGL(jpeg_codec_kernel, dim3(grid), dim3(256), 0, stream,
                     x, out);
}